// Round 6
// baseline (246.455 us; speedup 1.0000x reference)
//
#include <hip/hip_runtime.h>
#include <stdint.h>

typedef __bf16 bf16x8 __attribute__((ext_vector_type(8)));
typedef float f32x4v __attribute__((ext_vector_type(4)));
typedef float f32x16v __attribute__((ext_vector_type(16)));
typedef unsigned u32x2 __attribute__((ext_vector_type(2)));

__device__ __forceinline__ unsigned f2bf_rn(float f) {
    return (__float_as_uint(f) + 0x8000u) >> 16;
}
__device__ __forceinline__ unsigned pk2bf(float a, float b) {
    return __builtin_amdgcn_perm(__float_as_uint(b) + 0x8000u,
                                 __float_as_uint(a) + 0x8000u, 0x07060302u);
}

__device__ __forceinline__ void swap32(unsigned &a, unsigned &b) {
#if __has_builtin(__builtin_amdgcn_permlane32_swap)
    u32x2 r = __builtin_amdgcn_permlane32_swap(a, b, false, false);
    a = r[0]; b = r[1];
#else
    unsigned pa = (unsigned)__shfl_xor((int)a, 32);
    unsigned pb = (unsigned)__shfl_xor((int)b, 32);
    bool hi = (threadIdx.x & 32) != 0;
    unsigned na = hi ? pb : a;
    unsigned nb = hi ? b : pa;
    a = na; b = nb;
#endif
}

__device__ __forceinline__ bf16x8 mk8(unsigned a, unsigned b, unsigned c, unsigned e) {
    union { int4 i; bf16x8 v; } u;
    u.i = make_int4((int)a, (int)b, (int)c, (int)e);
    return u.v;
}

#define GLD_LDS16(gp, lp) __builtin_amdgcn_global_load_lds( \
    (const __attribute__((address_space(1))) unsigned int*)(gp), \
    (__attribute__((address_space(3))) unsigned int*)(lp), 16, 0, 0)

// ---------------- weight transposes (both matrices, one launch) ----------------
__global__ __launch_bounds__(256) void wt_kernel(const float* __restrict__ wqkv,
        const float* __restrict__ wout, unsigned short* __restrict__ WqT,
        unsigned short* __restrict__ WoT) {
    __shared__ float tile[32][33];
    int bx = blockIdx.x;
    const float* in; unsigned short* out; int Cc, c0;
    if (bx < 48) { in = wqkv; out = WqT; Cc = 1536; c0 = bx * 32; }
    else         { in = wout; out = WoT; Cc = 512;  c0 = (bx - 48) * 32; }
    int r0 = blockIdx.y * 32;
    int tx = threadIdx.x & 31, ty = threadIdx.x >> 5;
    #pragma unroll
    for (int i = 0; i < 4; i++) {
        int r = ty + i * 8;
        tile[r][tx] = in[(size_t)(r0 + r) * Cc + c0 + tx];
    }
    __syncthreads();
    #pragma unroll
    for (int i = 0; i < 4; i++) {
        int cr = ty + i * 8;
        out[(size_t)(c0 + cr) * 512 + r0 + tx] = (unsigned short)f2bf_rn(tile[tx][cr]);
    }
}

// ---------------- GroupNorm -> hnT bf16 [n][s][c] ----------------
__global__ __launch_bounds__(256) void gn_kernel(const float* __restrict__ x,
        const float* __restrict__ scale, const float* __restrict__ bias,
        unsigned short* __restrict__ hnT) {
    int blk = blockIdx.x;                  // n*32+g
    int tid = threadIdx.x;
    int g = blk & 31, n = blk >> 5;
    const float4* src4 = (const float4*)(x + (size_t)blk * 16384);

    float s = 0.f, s2 = 0.f;
    for (int i = tid; i < 4096; i += 256) {
        float4 v = src4[i];
        s  += v.x + v.y + v.z + v.w;
        s2 += v.x*v.x + v.y*v.y + v.z*v.z + v.w*v.w;
    }
    __shared__ float red[256], red2[256];
    red[tid] = s; red2[tid] = s2;
    __syncthreads();
    for (int off = 128; off > 0; off >>= 1) {
        if (tid < off) { red[tid] += red[tid+off]; red2[tid] += red2[tid+off]; }
        __syncthreads();
    }
    __shared__ float sc_s[16], bi_s[16];
    if (tid < 16) {
        float mean = red[0] * (1.f/16384.f);
        float var  = red2[0] * (1.f/16384.f) - mean*mean;
        float rstd = rsqrtf(var + 1e-6f);
        int c = g*16 + tid;
        float sc = scale[c] * rstd;
        sc_s[tid] = sc;
        bi_s[tid] = bias[c] - mean * sc;
    }
    __shared__ float tile[16][260];
    for (int ch = 0; ch < 4; ch++) {
        __syncthreads();
        #pragma unroll
        for (int kk = 0; kk < 4; kk++) {
            int fi = tid + kk*256;
            int row = fi >> 6, col4 = fi & 63;
            float4 v = src4[row*256 + ch*64 + col4];
            *(float4*)&tile[row][col4*4] = v;
        }
        __syncthreads();
        int sQ = ch*256 + tid;
        unsigned int pk[8];
        #pragma unroll
        for (int c2 = 0; c2 < 8; c2++) {
            float a = tile[c2*2][tid]   * sc_s[c2*2]   + bi_s[c2*2];
            float b = tile[c2*2+1][tid] * sc_s[c2*2+1] + bi_s[c2*2+1];
            pk[c2] = pk2bf(a, b);
        }
        unsigned short* op = hnT + ((size_t)(n*1024 + sQ))*512 + g*16;
        *(uint4*)op       = make_uint4(pk[0], pk[1], pk[2], pk[3]);
        *((uint4*)op + 1) = make_uint4(pk[4], pk[5], pk[6], pk[7]);
    }
}

// ---------------- QKV GEMM: D[m][s] = sum_c WqT[m][c]*hnT[s][c] ----------------
// Epilogue: LDS transpose per 64-m half -> fully coalesced q/k/v stores.
__global__ __launch_bounds__(256) void qkv_kernel(
        const unsigned short* __restrict__ WqT, const unsigned short* __restrict__ hnT,
        const float* __restrict__ bqkv,
        unsigned short* __restrict__ qb, unsigned short* __restrict__ kbuf,
        unsigned short* __restrict__ vb) {
    int s0 = blockIdx.x * 128, m0 = blockIdx.y * 128, n = blockIdx.z;
    __shared__ unsigned short SH[9216];    // At(4096) + Bt(4096) during loop; epilogue tile after
    unsigned short* At = SH;
    unsigned short* Bt = SH + 4096;
    int tid = threadIdx.x;
    int lane = tid & 63, w = tid >> 6;
    int quad = lane >> 4, tx = lane & 15;
    int moff = (w & 1) * 64, soff = (w >> 1) * 64;

    const unsigned short* Arow = WqT + (size_t)m0 * 512;
    const unsigned short* Brow = hnT + ((size_t)n * 1024 + s0) * 512;

    f32x4v acc[4][4];
    #pragma unroll
    for (int i = 0; i < 4; i++)
        #pragma unroll
        for (int j = 0; j < 4; j++)
            #pragma unroll
            for (int e = 0; e < 4; e++) acc[i][j][e] = 0.f;

    int f1 = tid, f2 = tid + 256;
    int m1 = f1 >> 2, kb1 = ((f1 & 3) - (f1 >> 3)) & 3;
    int m2 = f2 >> 2, kb2 = ((f2 & 3) - (f2 >> 3)) & 3;

    for (int k0 = 0; k0 < 512; k0 += 32) {
        __syncthreads();
        GLD_LDS16(Arow + (size_t)m1*512 + k0 + kb1*8, At + f1*8);
        GLD_LDS16(Arow + (size_t)m2*512 + k0 + kb2*8, At + f2*8);
        GLD_LDS16(Brow + (size_t)m1*512 + k0 + kb1*8, Bt + f1*8);
        GLD_LDS16(Brow + (size_t)m2*512 + k0 + kb2*8, Bt + f2*8);
        __syncthreads();
        bf16x8 af[4], bfr[4];
        #pragma unroll
        for (int mt = 0; mt < 4; mt++) {
            int m = moff + mt*16 + tx;
            int ch = m*4 + ((quad + (m >> 1)) & 3);
            af[mt] = *(const bf16x8*)(At + ch*8);
        }
        #pragma unroll
        for (int nt = 0; nt < 4; nt++) {
            int m = soff + nt*16 + tx;
            int ch = m*4 + ((quad + (m >> 1)) & 3);
            bfr[nt] = *(const bf16x8*)(Bt + ch*8);
        }
        #pragma unroll
        for (int mt = 0; mt < 4; mt++)
            #pragma unroll
            for (int nt = 0; nt < 4; nt++)
                acc[mt][nt] = __builtin_amdgcn_mfma_f32_16x16x32_bf16(
                    af[mt], bfr[nt], acc[mt][nt], 0, 0, 0);
    }

    __syncthreads();
    const float QSCL = 0.18033688011112042f;   // 0.125*log2(e); exp2-domain softmax
    #pragma unroll
    for (int h2 = 0; h2 < 2; h2++) {
        int mbase = m0 + h2*64;
        int head = mbase / 192;
        int rr = mbase - head*192;
        int which = rr >> 6;                   // 0=q 1=k 2=v, uniform per half
        float scl = (which == 0) ? QSCL : 1.0f;
        if ((w & 1) == h2) {                   // phase 1: acc half -> LDS
            #pragma unroll
            for (int mt = 0; mt < 4; mt++) {
                int m_rel = mt*16 + quad*4;
                float4 bia = *(const float4*)(bqkv + mbase + m_rel);
                #pragma unroll
                for (int nt = 0; nt < 4; nt++) {
                    int s_local = soff + nt*16 + tx;
                    f32x4v a = acc[mt][nt];
                    float v0=(a[0]+bia.x)*scl, v1=(a[1]+bia.y)*scl;
                    float v2=(a[2]+bia.z)*scl, v3=(a[3]+bia.w)*scl;
                    if (which < 2) {           // [s][m] rows, stride 72
                        *(uint2*)(SH + s_local*72 + m_rel) =
                            make_uint2(pk2bf(v0,v1), pk2bf(v2,v3));
                    } else {                   // [d][t] rows, stride 136
                        SH[(m_rel+0)*136 + s_local] = (unsigned short)f2bf_rn(v0);
                        SH[(m_rel+1)*136 + s_local] = (unsigned short)f2bf_rn(v1);
                        SH[(m_rel+2)*136 + s_local] = (unsigned short)f2bf_rn(v2);
                        SH[(m_rel+3)*136 + s_local] = (unsigned short)f2bf_rn(v3);
                    }
                }
            }
        }
        __syncthreads();
        if (which < 2) {                       // phase 2: 128 B-coalesced q/k rows
            unsigned short* basep = ((which==0)? qb : kbuf)
                + (((size_t)(n*8+head))*1024 + s0)*64;
            #pragma unroll
            for (int rd = 0; rd < 4; rd++) {
                int rrow = rd*32 + (tid>>3);
                int l8 = tid & 7;
                uint4 val = *(const uint4*)(SH + rrow*72 + l8*8);
                *(uint4*)(basep + rrow*64 + l8*8) = val;
            }
        } else {                               // 256 B-coalesced v rows
            unsigned short* basep = vb + (((size_t)(n*8+head))*64)*1024 + s0;
            #pragma unroll
            for (int rd = 0; rd < 4; rd++) {
                int drow = rd*16 + (tid>>4);
                int ch = tid & 15;
                uint4 val = *(const uint4*)(SH + drow*136 + ch*8);
                *(uint4*)(basep + (size_t)drow*1024 + ch*8) = val;
            }
        }
        __syncthreads();
    }
}

// ---------------- flash attention: in-register P transpose, pipelined staging ----
__global__ __launch_bounds__(256) void attn_kernel(
        const unsigned short* __restrict__ qg, const unsigned short* __restrict__ kg,
        const unsigned short* __restrict__ vg, unsigned short* __restrict__ ao) {
    int bid = blockIdx.x;
    int nh = bid & 127, qbk = bid >> 7;     // 8 q-blocks of one head share an XCD
    int tid = threadIdx.x, w = tid >> 6, lane = tid & 63;
    int lq = lane & 31, hi = lane >> 5;
    const unsigned short* Q = qg + (size_t)nh * 65536;
    const unsigned short* K = kg + (size_t)nh * 65536;
    const unsigned short* V = vg + (size_t)nh * 65536;   // [d][t]

    __shared__ unsigned short Klds[2][64*72];            // [t][d], pad 8
    __shared__ unsigned short Vlds[2][64*72];            // [d][t], pad 8
    __shared__ float lsum_s[4][32];

    int q0 = qbk*128 + w*32;
    bf16x8 qf[4];
    #pragma unroll
    for (int ks = 0; ks < 4; ks++)
        qf[ks] = *(const bf16x8*)(Q + ((size_t)(q0 + lq))*64 + ks*16 + hi*8);

    int r = tid >> 2, part = (tid & 3) * 16;
    uint4 ka, kb2, va, vb2;
    ka  = *(const uint4*)(K + (size_t)r*64 + part);
    kb2 = *(const uint4*)(K + (size_t)r*64 + part + 8);
    va  = *(const uint4*)(V + (size_t)r*1024 + part);
    vb2 = *(const uint4*)(V + (size_t)r*1024 + part + 8);

    f32x16v O0, O1;
    #pragma unroll
    for (int i = 0; i < 16; i++) { O0[i] = 0.f; O1[i] = 0.f; }
    float lsum = 0.f;

    for (int it = 0; it < 16; it++) {
        int buf = it & 1;
        {
            unsigned short* kd = Klds[buf] + r*72 + part;
            *(uint4*)kd = ka; *(uint4*)(kd+8) = kb2;
            unsigned short* vd = Vlds[buf] + r*72 + part;
            *(uint4*)vd = va; *(uint4*)(vd+8) = vb2;
        }
        __syncthreads();
        if (it < 15) {
            int t0 = (it + 1) * 64;
            ka  = *(const uint4*)(K + (size_t)(t0 + r)*64 + part);
            kb2 = *(const uint4*)(K + (size_t)(t0 + r)*64 + part + 8);
            va  = *(const uint4*)(V + (size_t)r*1024 + t0 + part);
            vb2 = *(const uint4*)(V + (size_t)r*1024 + t0 + part + 8);
        }
        const unsigned short* Kb = Klds[buf];
        const unsigned short* Vb = Vlds[buf];

        f32x16v S0, S1;
        #pragma unroll
        for (int i = 0; i < 16; i++) { S0[i] = 0.f; S1[i] = 0.f; }
        #pragma unroll
        for (int ks = 0; ks < 4; ks++) {
            bf16x8 a0 = *(const bf16x8*)(Kb + lq*72 + ks*16 + hi*8);
            bf16x8 a1 = *(const bf16x8*)(Kb + (32+lq)*72 + ks*16 + hi*8);
            S0 = __builtin_amdgcn_mfma_f32_32x32x16_bf16(a0, qf[ks], S0, 0, 0, 0);
            S1 = __builtin_amdgcn_mfma_f32_32x32x16_bf16(a1, qf[ks], S1, 0, 0, 0);
        }

        #pragma unroll
        for (int i = 0; i < 16; i++) {
            S0[i] = exp2f(S0[i]);
            S1[i] = exp2f(S1[i]);
            lsum += S0[i] + S1[i];
        }
        unsigned d[16];
        #pragma unroll
        for (int p2 = 0; p2 < 8; p2++) {
            d[p2]     = pk2bf(S0[p2*2], S0[p2*2+1]);
            d[8 + p2] = pk2bf(S1[p2*2], S1[p2*2+1]);
        }
        swap32(d[0],  d[2]);  swap32(d[1],  d[3]);
        swap32(d[4],  d[6]);  swap32(d[5],  d[7]);
        swap32(d[8],  d[10]); swap32(d[9],  d[11]);
        swap32(d[12], d[14]); swap32(d[13], d[15]);

        #pragma unroll
        for (int kc = 0; kc < 4; kc++) {
            bf16x8 pa = mk8(d[kc*4+0], d[kc*4+1], d[kc*4+2], d[kc*4+3]);
            bf16x8 v0 = *(const bf16x8*)(Vb + lq*72 + kc*16 + hi*8);
            bf16x8 v1 = *(const bf16x8*)(Vb + (32+lq)*72 + kc*16 + hi*8);
            O0 = __builtin_amdgcn_mfma_f32_32x32x16_bf16(pa, v0, O0, 0, 0, 0);
            O1 = __builtin_amdgcn_mfma_f32_32x32x16_bf16(pa, v1, O1, 0, 0, 0);
        }
    }

    lsum += __shfl_xor(lsum, 32);
    lsum_s[w][lq] = lsum;
    int n = nh >> 3, h = nh & 7;
    #pragma unroll
    for (int rq = 0; rq < 4; rq++) {
        float4 lv = *(const float4*)&lsum_s[w][rq*8 + hi*4];
        float invs[4] = {1.f/lv.x, 1.f/lv.y, 1.f/lv.z, 1.f/lv.w};
        #pragma unroll
        for (int i = 0; i < 4; i++) {
            int sQ = q0 + rq*8 + hi*4 + i;
            size_t rowb = ((size_t)(n*1024 + sQ))*512 + h*64;
            ao[rowb + lq]      = (unsigned short)f2bf_rn(O0[rq*4+i] * invs[i]);
            ao[rowb + 32 + lq] = (unsigned short)f2bf_rn(O1[rq*4+i] * invs[i]);
        }
    }
}

// ---------------- out GEMM: D[s][d] = sum_c aoT[s][c]*WoT[d][c]; +bias+x ----------------
// Epilogue: LDS transpose per 64-d half -> 512 B-coalesced x-read + store.
__global__ __launch_bounds__(256) void out_kernel(
        const unsigned short* __restrict__ aoT, const unsigned short* __restrict__ WoT,
        const float* __restrict__ bout, const float* __restrict__ x,
        float* __restrict__ out) {
    int s0 = blockIdx.x * 128, d0b = blockIdx.y * 128, n = blockIdx.z;
    __shared__ float Tf[64*132];           // 33.8 KB; aliases At/Bt during loop
    unsigned short* At = (unsigned short*)Tf;
    unsigned short* Bt = At + 4096;
    int tid = threadIdx.x;
    int lane = tid & 63, w = tid >> 6;
    int quad = lane >> 4, tx = lane & 15;
    int moff = (w & 1) * 64, noff = (w >> 1) * 64;

    const unsigned short* Arow = aoT + ((size_t)n * 1024 + s0) * 512;
    const unsigned short* Brow = WoT + (size_t)d0b * 512;

    f32x4v acc[4][4];
    #pragma unroll
    for (int i = 0; i < 4; i++)
        #pragma unroll
        for (int j = 0; j < 4; j++)
            #pragma unroll
            for (int e = 0; e < 4; e++) acc[i][j][e] = 0.f;

    int f1 = tid, f2 = tid + 256;
    int m1 = f1 >> 2, kb1 = ((f1 & 3) - (f1 >> 3)) & 3;
    int m2 = f2 >> 2, kb2 = ((f2 & 3) - (f2 >> 3)) & 3;

    for (int k0 = 0; k0 < 512; k0 += 32) {
        __syncthreads();
        GLD_LDS16(Arow + (size_t)m1*512 + k0 + kb1*8, At + f1*8);
        GLD_LDS16(Arow + (size_t)m2*512 + k0 + kb2*8, At + f2*8);
        GLD_LDS16(Brow + (size_t)m1*512 + k0 + kb1*8, Bt + f1*8);
        GLD_LDS16(Brow + (size_t)m2*512 + k0 + kb2*8, Bt + f2*8);
        __syncthreads();
        bf16x8 af[4], bfr[4];
        #pragma unroll
        for (int mt = 0; mt < 4; mt++) {
            int m = moff + mt*16 + tx;
            int ch = m*4 + ((quad + (m >> 1)) & 3);
            af[mt] = *(const bf16x8*)(At + ch*8);
        }
        #pragma unroll
        for (int nt = 0; nt < 4; nt++) {
            int m = noff + nt*16 + tx;
            int ch = m*4 + ((quad + (m >> 1)) & 3);
            bfr[nt] = *(const bf16x8*)(Bt + ch*8);
        }
        #pragma unroll
        for (int mt = 0; mt < 4; mt++)
            #pragma unroll
            for (int nt = 0; nt < 4; nt++)
                acc[mt][nt] = __builtin_amdgcn_mfma_f32_16x16x32_bf16(
                    af[mt], bfr[nt], acc[mt][nt], 0, 0, 0);
    }

    __syncthreads();
    #pragma unroll
    for (int h2 = 0; h2 < 2; h2++) {
        if ((w >> 1) == h2) {              // phase 1: acc half -> LDS [d][s] f32
            #pragma unroll
            for (int mt = 0; mt < 4; mt++) {
                int s_local = moff + mt*16 + quad*4;
                #pragma unroll
                for (int nt = 0; nt < 4; nt++) {
                    int drel = nt*16 + tx;
                    f32x4v a = acc[mt][nt];
                    *(float4*)(Tf + drel*132 + s_local) =
                        make_float4(a[0], a[1], a[2], a[3]);
                }
            }
        }
        __syncthreads();
        #pragma unroll
        for (int rd = 0; rd < 8; rd++) {   // phase 2: 512 B-coalesced rows
            int drel = rd*8 + (tid>>5);
            int l32 = tid & 31;
            int d = d0b + h2*64 + drel;
            float4 v = *(const float4*)(Tf + drel*132 + l32*4);
            size_t base = ((size_t)n*512 + d)*1024 + s0 + l32*4;
            float4 xv = *(const float4*)(x + base);
            float bo = bout[d];
            *(float4*)(out + base) =
                make_float4(v.x+bo+xv.x, v.y+bo+xv.y, v.z+bo+xv.z, v.w+bo+xv.w);
        }
        __syncthreads();
    }
}

extern "C" void kernel_launch(void* const* d_in, const int* in_sizes, int n_in,
                              void* d_out, int out_size, void* d_ws, size_t ws_size,
                              hipStream_t stream) {
    const float* x    = (const float*)d_in[0];
    const float* gns  = (const float*)d_in[1];
    const float* gnb  = (const float*)d_in[2];
    const float* wqkv = (const float*)d_in[3];
    const float* bqkv = (const float*)d_in[4];
    const float* wout = (const float*)d_in[5];
    const float* bout = (const float*)d_in[6];
    float* out = (float*)d_out;

    char* p = (char*)d_ws;
    size_t off = 0;
    auto carve = [&](size_t bytes) {
        char* r = p + off;
        off = (off + bytes + 255) & ~(size_t)255;
        return r;
    };
    unsigned short* hnT = (unsigned short*)carve((size_t)16*1024*512*2);
    unsigned short* qb2 = (unsigned short*)carve((size_t)128*1024*64*2);
    unsigned short* kb2 = (unsigned short*)carve((size_t)128*1024*64*2);
    unsigned short* vb2 = (unsigned short*)carve((size_t)128*64*1024*2);
    unsigned short* aoT = (unsigned short*)carve((size_t)16*1024*512*2);
    unsigned short* WqT = (unsigned short*)carve((size_t)1536*512*2);
    unsigned short* WoT = (unsigned short*)carve((size_t)512*512*2);

    wt_kernel<<<dim3(64, 16), 256, 0, stream>>>(wqkv, wout, WqT, WoT);
    gn_kernel<<<dim3(512), 256, 0, stream>>>(x, gns, gnb, hnT);
    qkv_kernel<<<dim3(8, 12, 16), 256, 0, stream>>>(WqT, hnT, bqkv, qb2, kb2, vb2);
    attn_kernel<<<dim3(1024), 256, 0, stream>>>(qb2, kb2, vb2, aoT);
    out_kernel<<<dim3(8, 4, 16), 256, 0, stream>>>(aoT, WoT, bout, x, out);
}